// Round 1
// baseline (583.102 us; speedup 1.0000x reference)
//
#include <hip/hip_runtime.h>
#include <hip/hip_bf16.h>

typedef _Float16 half8 __attribute__((ext_vector_type(8)));
typedef float f32x4 __attribute__((ext_vector_type(4)));

#define KDIM 1024
#define NDIM 1024
#define MROWS 16384   // B*L = 4*4096

// ---------------------------------------------------------------------------
// Generic Y = act(X @ W^T + bias) GEMM.
// X: [MROWS][1024] (fp32 or fp16), W: [1024][1024] fp32 row-major, bias [1024].
// Tile 128x128, BK=64, 4 waves (2x2 of 64x64), mfma_f32_16x16x32_f16.
// LDS XOR-swizzle (byte ^= (row&7)<<4) to avoid 128B-stride bank conflicts.
// ACT: 0 = none, 1 = elu(x)+1
// ---------------------------------------------------------------------------
template <typename TA, int ACT, typename TOUT>
__global__ __launch_bounds__(256, 2)
void gemm_xwt(const TA* __restrict__ X, const float* __restrict__ W,
              const float* __restrict__ bias, TOUT* __restrict__ Y) {
  constexpr int BM = 128, BN = 128, BK = 64;
  __shared__ _Float16 As[BM * BK];
  __shared__ _Float16 Bs[BN * BK];
  const int tid  = threadIdx.x;
  const int lane = tid & 63;
  const int w    = tid >> 6;
  const int wr   = (w >> 1) * 64;
  const int wc   = (w & 1) * 64;
  const int m0   = blockIdx.x * BM;
  const int n0   = blockIdx.y * BN;

  f32x4 acc[4][4] = {};

  for (int k0 = 0; k0 < KDIM; k0 += BK) {
    __syncthreads();
    // ---- stage A (X) and B (W) tiles: 128 rows x 64 cols each, fp16 in LDS
#pragma unroll
    for (int j = 0; j < 4; ++j) {
      int c    = tid + 256 * j;     // 0..1023
      int row  = c >> 3;            // 0..127
      int col8 = (c & 7) << 3;      // 0,8,..,56
      int byte = row * (BK * 2) + (col8 << 1);
      byte ^= (row & 7) << 4;

      half8 ha;
      if constexpr (sizeof(TA) == 4) {
        const float* src = (const float*)X + (size_t)(m0 + row) * KDIM + k0 + col8;
        float4 f0 = *(const float4*)src;
        float4 f1 = *(const float4*)(src + 4);
        ha[0] = (_Float16)f0.x; ha[1] = (_Float16)f0.y;
        ha[2] = (_Float16)f0.z; ha[3] = (_Float16)f0.w;
        ha[4] = (_Float16)f1.x; ha[5] = (_Float16)f1.y;
        ha[6] = (_Float16)f1.z; ha[7] = (_Float16)f1.w;
      } else {
        ha = *(const half8*)((const _Float16*)X + (size_t)(m0 + row) * KDIM + k0 + col8);
      }
      *(half8*)((char*)As + byte) = ha;

      const float* wsrc = W + (size_t)(n0 + row) * KDIM + k0 + col8;
      float4 g0 = *(const float4*)wsrc;
      float4 g1 = *(const float4*)(wsrc + 4);
      half8 hb;
      hb[0] = (_Float16)g0.x; hb[1] = (_Float16)g0.y;
      hb[2] = (_Float16)g0.z; hb[3] = (_Float16)g0.w;
      hb[4] = (_Float16)g1.x; hb[5] = (_Float16)g1.y;
      hb[6] = (_Float16)g1.z; hb[7] = (_Float16)g1.w;
      *(half8*)((char*)Bs + byte) = hb;
    }
    __syncthreads();

    // ---- fragments + MFMA
    half8 afr[4][2], bfr[4][2];
#pragma unroll
    for (int m = 0; m < 4; ++m)
#pragma unroll
      for (int kk = 0; kk < 2; ++kk) {
        int row  = wr + m * 16 + (lane & 15);
        int byte = row * 128 + ((lane >> 4) << 4) + kk * 64;
        byte ^= (row & 7) << 4;
        afr[m][kk] = *(const half8*)((const char*)As + byte);
      }
#pragma unroll
    for (int n = 0; n < 4; ++n)
#pragma unroll
      for (int kk = 0; kk < 2; ++kk) {
        int row  = wc + n * 16 + (lane & 15);
        int byte = row * 128 + ((lane >> 4) << 4) + kk * 64;
        byte ^= (row & 7) << 4;
        bfr[n][kk] = *(const half8*)((const char*)Bs + byte);
      }
#pragma unroll
    for (int kk = 0; kk < 2; ++kk)
#pragma unroll
      for (int m = 0; m < 4; ++m)
#pragma unroll
        for (int n = 0; n < 4; ++n)
          acc[m][n] = __builtin_amdgcn_mfma_f32_16x16x32_f16(afr[m][kk], bfr[n][kk],
                                                             acc[m][n], 0, 0, 0);
  }

  // ---- epilogue: bias + activation + store
#pragma unroll
  for (int n = 0; n < 4; ++n) {
    int col  = n0 + wc + n * 16 + (lane & 15);
    float bv = bias[col];
#pragma unroll
    for (int m = 0; m < 4; ++m) {
#pragma unroll
      for (int i = 0; i < 4; ++i) {
        int row = m0 + wr + m * 16 + ((lane >> 4) << 2) + i;
        float v = acc[m][n][i] + bv;
        if constexpr (ACT == 1) v = (v > 0.f) ? (v + 1.f) : __expf(v);
        Y[(size_t)row * NDIM + col] = (TOUT)v;
      }
    }
  }
}

// ---------------------------------------------------------------------------
// KV partial: per (bh, chunk) block reduce 512 rows:
//   KV[d][e] += K[l][d]*V[l][e],  Ksum[d] += K[l][d]
// Output layout per (ch,bh): [4096 kv (d*64+e)][64 ksum]
// ---------------------------------------------------------------------------
__global__ __launch_bounds__(256)
void kv_partial(const _Float16* __restrict__ Kp, const _Float16* __restrict__ Vp,
                float* __restrict__ pKV) {
  const int bh = blockIdx.x;      // 0..63
  const int ch = blockIdx.y;      // 0..7
  const int b  = bh >> 4, h = bh & 15;
  const int tid = threadIdx.x;
  const int d  = tid & 63;
  const int eb = (tid >> 6) << 4;  // 0,16,32,48

  __shared__ _Float16 Ks[64 * 64];
  __shared__ _Float16 Vs[64 * 64];

  float acc[16] = {};
  float ksum = 0.f;

  const size_t rowbase = (size_t)b * 4096 + (size_t)ch * 512;

  for (int s = 0; s < 8; ++s) {
    __syncthreads();
#pragma unroll
    for (int j = 0; j < 2; ++j) {
      int c    = tid + 256 * j;    // 0..511
      int row  = c >> 3;           // 0..63
      int col8 = (c & 7) << 3;
      size_t g = (rowbase + s * 64 + row) * KDIM + h * 64 + col8;
      *(half8*)&Ks[row * 64 + col8] = *(const half8*)(Kp + g);
      *(half8*)&Vs[row * 64 + col8] = *(const half8*)(Vp + g);
    }
    __syncthreads();
#pragma unroll 4
    for (int l = 0; l < 64; ++l) {
      float kd = (float)Ks[l * 64 + d];
      ksum += kd;
      half8 v0 = *(const half8*)&Vs[l * 64 + eb];
      half8 v1 = *(const half8*)&Vs[l * 64 + eb + 8];
#pragma unroll
      for (int e = 0; e < 8; ++e) {
        acc[e]     += kd * (float)v0[e];
        acc[e + 8] += kd * (float)v1[e];
      }
    }
  }

  float* outp = pKV + ((size_t)ch * 64 + bh) * 4160;
#pragma unroll
  for (int e = 0; e < 16; ++e) outp[d * 64 + eb + e] = acc[e];
  if (tid < 64) outp[4096 + d] = ksum;
}

// ---------------------------------------------------------------------------
// Combine 8 partials -> KVTx fp16 [64 bh][80 rows][64 cols]:
//   rows 0..63: KVT[e][d] = KV[d][e]; row 64: Ksum[d]; rows 65..79: 0
// ---------------------------------------------------------------------------
__global__ __launch_bounds__(256)
void kv_combine(const float* __restrict__ pKV, _Float16* __restrict__ KVTx) {
  int g = blockIdx.x * 256 + threadIdx.x;   // 0..327679
  int bh = g / 5120;
  int j  = g - bh * 5120;
  int e  = j >> 6;       // row 0..79
  int dc = j & 63;
  float s = 0.f;
  if (e < 64) {
#pragma unroll
    for (int ch = 0; ch < 8; ++ch)
      s += pKV[((size_t)ch * 64 + bh) * 4160 + dc * 64 + e];
  } else if (e == 64) {
#pragma unroll
    for (int ch = 0; ch < 8; ++ch)
      s += pKV[((size_t)ch * 64 + bh) * 4160 + 4096 + dc];
  }
  KVTx[(size_t)bh * 5120 + j] = (_Float16)s;
}

// ---------------------------------------------------------------------------
// attn: per (mtile, bh): att[m][e] = Z(m) * sum_d Q[m][d]*KV[d][e]
// B tile has 80 rows: 64 KVT rows + Ksum row (64) + 15 zero rows; the 5th
// n-fragment's column 0 yields the Z denominator per row via the same MFMA.
// ---------------------------------------------------------------------------
__global__ __launch_bounds__(256, 2)
void attn_kernel(const _Float16* __restrict__ Qp, const _Float16* __restrict__ KVTx,
                 _Float16* __restrict__ att) {
  const int mt = blockIdx.x;      // 0..31
  const int bh = blockIdx.y;      // 0..63
  const int b  = bh >> 4, h = bh & 15;
  const int tid = threadIdx.x;
  const int lane = tid & 63;
  const int w = tid >> 6;
  const size_t m0 = (size_t)b * 4096 + (size_t)mt * 128;

  __shared__ _Float16 As[128 * 64];
  __shared__ _Float16 Bs[80 * 64];

  // stage Q tile (128x64)
#pragma unroll
  for (int j = 0; j < 4; ++j) {
    int c    = tid + 256 * j;
    int row  = c >> 3;
    int col8 = (c & 7) << 3;
    int byte = row * 128 + (col8 << 1);
    byte ^= (row & 7) << 4;
    *(half8*)((char*)As + byte) =
        *(const half8*)(Qp + (m0 + row) * KDIM + h * 64 + col8);
  }
  // stage KVTx (80x64)
  for (int c = tid; c < 640; c += 256) {
    int row  = c >> 3;
    int col8 = (c & 7) << 3;
    int byte = row * 128 + (col8 << 1);
    byte ^= (row & 7) << 4;
    *(half8*)((char*)Bs + byte) = *(const half8*)(KVTx + (size_t)bh * 5120 + c * 8);
  }
  __syncthreads();

  f32x4 acc[2][5] = {};
  half8 afr[2][2], bfr[5][2];
#pragma unroll
  for (int m = 0; m < 2; ++m)
#pragma unroll
    for (int kk = 0; kk < 2; ++kk) {
      int row  = w * 32 + m * 16 + (lane & 15);
      int byte = row * 128 + ((lane >> 4) << 4) + kk * 64;
      byte ^= (row & 7) << 4;
      afr[m][kk] = *(const half8*)((const char*)As + byte);
    }
#pragma unroll
  for (int n = 0; n < 5; ++n)
#pragma unroll
    for (int kk = 0; kk < 2; ++kk) {
      int row  = n * 16 + (lane & 15);
      int byte = row * 128 + ((lane >> 4) << 4) + kk * 64;
      byte ^= (row & 7) << 4;
      bfr[n][kk] = *(const half8*)((const char*)Bs + byte);
    }
#pragma unroll
  for (int kk = 0; kk < 2; ++kk)
#pragma unroll
    for (int m = 0; m < 2; ++m)
#pragma unroll
      for (int n = 0; n < 5; ++n)
        acc[m][n] = __builtin_amdgcn_mfma_f32_16x16x32_f16(afr[m][kk], bfr[n][kk],
                                                           acc[m][n], 0, 0, 0);

#pragma unroll
  for (int m = 0; m < 2; ++m) {
#pragma unroll
    for (int i = 0; i < 4; ++i) {
      float dn = __shfl(acc[m][4][i], lane & 48);
      float z  = 1.f / (dn + 1e-6f);
      size_t row = m0 + w * 32 + m * 16 + ((lane >> 4) << 2) + i;
#pragma unroll
      for (int n = 0; n < 4; ++n) {
        att[row * NDIM + h * 64 + n * 16 + (lane & 15)] =
            (_Float16)(acc[m][n][i] * z);
      }
    }
  }
}

// ---------------------------------------------------------------------------
extern "C" void kernel_launch(void* const* d_in, const int* in_sizes, int n_in,
                              void* d_out, int out_size, void* d_ws, size_t ws_size,
                              hipStream_t stream) {
  const float* q  = (const float*)d_in[0];
  const float* k  = (const float*)d_in[1];
  const float* v  = (const float*)d_in[2];
  const float* wq = (const float*)d_in[3];
  const float* bq = (const float*)d_in[4];
  const float* wk = (const float*)d_in[5];
  const float* bk = (const float*)d_in[6];
  const float* wv = (const float*)d_in[7];
  const float* bv = (const float*)d_in[8];
  const float* wo = (const float*)d_in[9];
  const float* bo = (const float*)d_in[10];
  float* out = (float*)d_out;

  char* ws = (char*)d_ws;
  _Float16* Qp   = (_Float16*)(ws);                    // 33,554,432 B
  _Float16* Kp   = (_Float16*)(ws + 33554432);         // 33,554,432 B
  _Float16* Vp   = (_Float16*)(ws + 67108864);         // 33,554,432 B
  _Float16* att  = Kp;                                 // reuse Kp after KV built
  float*    pKV  = (float*)(ws + 100663296);           // 8,519,680 B
  _Float16* KVTx = (_Float16*)(ws + 109182976);        // 655,360 B

  dim3 gproj(MROWS / 128, NDIM / 128);
  gemm_xwt<float, 1, _Float16><<<gproj, 256, 0, stream>>>(q, wq, bq, Qp);
  gemm_xwt<float, 1, _Float16><<<gproj, 256, 0, stream>>>(k, wk, bk, Kp);
  gemm_xwt<float, 0, _Float16><<<gproj, 256, 0, stream>>>(v, wv, bv, Vp);

  kv_partial<<<dim3(64, 8), 256, 0, stream>>>(Kp, Vp, pKV);
  kv_combine<<<1280, 256, 0, stream>>>(pKV, KVTx);

  attn_kernel<<<dim3(32, 64), 256, 0, stream>>>(Qp, KVTx, att);

  gemm_xwt<_Float16, 0, float><<<gproj, 256, 0, stream>>>(att, wo, bo, out);
}

// Round 2
// 344.943 us; speedup vs baseline: 1.6904x; 1.6904x over previous
//
#include <hip/hip_runtime.h>
#include <hip/hip_bf16.h>

typedef _Float16 half8 __attribute__((ext_vector_type(8)));
typedef float f32x4 __attribute__((ext_vector_type(4)));

#define KDIM 1024
#define NDIM 1024
#define MROWS 16384   // B*L = 4*4096

#define GLD_LDS16(g, l)                                                  \
  __builtin_amdgcn_global_load_lds(                                      \
      (const __attribute__((address_space(1))) void*)(g),                \
      (__attribute__((address_space(3))) void*)(l), 16, 0, 0)

// ---------------------------------------------------------------------------
// fp32 -> fp16 convert, 8 elems/thread, grid-stride
// ---------------------------------------------------------------------------
__global__ __launch_bounds__(256)
void cvt_f32_to_f16(const float* __restrict__ src, _Float16* __restrict__ dst,
                    int n8) {
  for (int i = blockIdx.x * 256 + threadIdx.x; i < n8; i += gridDim.x * 256) {
    float4 f0 = ((const float4*)src)[2 * i];
    float4 f1 = ((const float4*)src)[2 * i + 1];
    half8 h;
    h[0] = (_Float16)f0.x; h[1] = (_Float16)f0.y;
    h[2] = (_Float16)f0.z; h[3] = (_Float16)f0.w;
    h[4] = (_Float16)f1.x; h[5] = (_Float16)f1.y;
    h[6] = (_Float16)f1.z; h[7] = (_Float16)f1.w;
    ((half8*)dst)[i] = h;
  }
}

// ---------------------------------------------------------------------------
// Y = act(X @ W^T + bias), all-fp16 inputs, m97 structure:
// 128x128 tile, BK=64, 4 waves (2x2 of 64x64), global_load_lds width=16,
// linear LDS dest + inverse-swizzled global source + XOR-swizzled ds_read
// (rule 21), mfma_f32_16x16x32_f16, fp32 accum.
// ACT: 0 = none, 1 = elu(x)+1
// ---------------------------------------------------------------------------
template <int ACT, typename TOUT>
__global__ __launch_bounds__(256, 2)
void gemm_h(const _Float16* __restrict__ X, const _Float16* __restrict__ W,
            const float* __restrict__ bias, TOUT* __restrict__ Y) {
  constexpr int BM = 128, BN = 128, BK = 64;
  __shared__ _Float16 As[BM * BK];
  __shared__ _Float16 Bs[BN * BK];
  const int tid  = threadIdx.x;
  const int lane = tid & 63;
  const int w    = tid >> 6;
  const int wr   = (w >> 1) * 64;
  const int wc   = (w & 1) * 64;
  const int m0   = blockIdx.x * BM;
  const int n0   = blockIdx.y * BN;

  // staging: each wave stages 32 rows of A and 32 rows of B (4 chunks of
  // 8 rows x 64 cols = 1024B each). Lane l covers row (l>>3), 16B-slot
  // (l&7) of its chunk; source slot is XOR'd with row&7 so that a
  // XOR-swizzled ds_read retrieves linear data (rule 21).
  const int lr = lane >> 3;          // row within 8-row chunk == row&7
  const int ls = (lane & 7) ^ lr;    // inverse-swizzled 16B slot
  const _Float16* gA = X + (size_t)(m0 + w * 32 + lr) * KDIM + ls * 8;
  const _Float16* gB = W + (size_t)(n0 + w * 32 + lr) * KDIM + ls * 8;
  _Float16* ldsA = As + (w * 32) * BK;
  _Float16* ldsB = Bs + (w * 32) * BK;

  f32x4 acc[4][4] = {};

  for (int k0 = 0; k0 < KDIM; k0 += BK) {
    __syncthreads();
#pragma unroll
    for (int c = 0; c < 4; ++c) {
      GLD_LDS16(gA + k0 + (size_t)(c * 8) * KDIM, ldsA + c * 8 * BK);
      GLD_LDS16(gB + k0 + (size_t)(c * 8) * KDIM, ldsB + c * 8 * BK);
    }
    __syncthreads();   // drains vmcnt(0): LDS tiles ready

    half8 afr[4][2], bfr[4][2];
#pragma unroll
    for (int m = 0; m < 4; ++m)
#pragma unroll
      for (int kk = 0; kk < 2; ++kk) {
        int row  = wr + m * 16 + (lane & 15);
        int byte = row * 128 + ((lane >> 4) << 4) + kk * 64;
        byte ^= (row & 7) << 4;
        afr[m][kk] = *(const half8*)((const char*)As + byte);
      }
#pragma unroll
    for (int n = 0; n < 4; ++n)
#pragma unroll
      for (int kk = 0; kk < 2; ++kk) {
        int row  = wc + n * 16 + (lane & 15);
        int byte = row * 128 + ((lane >> 4) << 4) + kk * 64;
        byte ^= (row & 7) << 4;
        bfr[n][kk] = *(const half8*)((const char*)Bs + byte);
      }
#pragma unroll
    for (int kk = 0; kk < 2; ++kk)
#pragma unroll
      for (int m = 0; m < 4; ++m)
#pragma unroll
        for (int n = 0; n < 4; ++n)
          acc[m][n] = __builtin_amdgcn_mfma_f32_16x16x32_f16(afr[m][kk], bfr[n][kk],
                                                             acc[m][n], 0, 0, 0);
  }

  // epilogue: bias + activation + store (verified C/D mapping from round 1)
#pragma unroll
  for (int n = 0; n < 4; ++n) {
    int col  = n0 + wc + n * 16 + (lane & 15);
    float bv = bias[col];
#pragma unroll
    for (int m = 0; m < 4; ++m) {
#pragma unroll
      for (int i = 0; i < 4; ++i) {
        int row = m0 + wr + m * 16 + ((lane >> 4) << 2) + i;
        float v = acc[m][n][i] + bv;
        if constexpr (ACT == 1) v = (v > 0.f) ? (v + 1.f) : __expf(v);
        Y[(size_t)row * NDIM + col] = (TOUT)v;
      }
    }
  }
}

// ---------------------------------------------------------------------------
// KV partial: per (bh, chunk) block reduce 512 rows:
//   KV[d][e] += K[l][d]*V[l][e],  Ksum[d] += K[l][d]
// Output layout per (ch,bh): [4096 kv (d*64+e)][64 ksum]
// ---------------------------------------------------------------------------
__global__ __launch_bounds__(256)
void kv_partial(const _Float16* __restrict__ Kp, const _Float16* __restrict__ Vp,
                float* __restrict__ pKV) {
  const int bh = blockIdx.x;      // 0..63
  const int ch = blockIdx.y;      // 0..7
  const int b  = bh >> 4, h = bh & 15;
  const int tid = threadIdx.x;
  const int d  = tid & 63;
  const int eb = (tid >> 6) << 4;  // 0,16,32,48

  __shared__ _Float16 Ks[64 * 64];
  __shared__ _Float16 Vs[64 * 64];

  float acc[16] = {};
  float ksum = 0.f;

  const size_t rowbase = (size_t)b * 4096 + (size_t)ch * 512;

  for (int s = 0; s < 8; ++s) {
    __syncthreads();
#pragma unroll
    for (int j = 0; j < 2; ++j) {
      int c    = tid + 256 * j;    // 0..511
      int row  = c >> 3;           // 0..63
      int col8 = (c & 7) << 3;
      size_t g = (rowbase + s * 64 + row) * KDIM + h * 64 + col8;
      *(half8*)&Ks[row * 64 + col8] = *(const half8*)(Kp + g);
      *(half8*)&Vs[row * 64 + col8] = *(const half8*)(Vp + g);
    }
    __syncthreads();
#pragma unroll 4
    for (int l = 0; l < 64; ++l) {
      float kd = (float)Ks[l * 64 + d];
      ksum += kd;
      half8 v0 = *(const half8*)&Vs[l * 64 + eb];
      half8 v1 = *(const half8*)&Vs[l * 64 + eb + 8];
#pragma unroll
      for (int e = 0; e < 8; ++e) {
        acc[e]     += kd * (float)v0[e];
        acc[e + 8] += kd * (float)v1[e];
      }
    }
  }

  float* outp = pKV + ((size_t)ch * 64 + bh) * 4160;
#pragma unroll
  for (int e = 0; e < 16; ++e) outp[d * 64 + eb + e] = acc[e];
  if (tid < 64) outp[4096 + d] = ksum;
}

// ---------------------------------------------------------------------------
// Combine 8 partials -> KVTx fp16 [64 bh][80 rows][64 cols]:
//   rows 0..63: KVT[e][d] = KV[d][e]; row 64: Ksum[d]; rows 65..79: 0
// ---------------------------------------------------------------------------
__global__ __launch_bounds__(256)
void kv_combine(const float* __restrict__ pKV, _Float16* __restrict__ KVTx) {
  int g = blockIdx.x * 256 + threadIdx.x;   // 0..327679
  int bh = g / 5120;
  int j  = g - bh * 5120;
  int e  = j >> 6;       // row 0..79
  int dc = j & 63;
  float s = 0.f;
  if (e < 64) {
#pragma unroll
    for (int ch = 0; ch < 8; ++ch)
      s += pKV[((size_t)ch * 64 + bh) * 4160 + dc * 64 + e];
  } else if (e == 64) {
#pragma unroll
    for (int ch = 0; ch < 8; ++ch)
      s += pKV[((size_t)ch * 64 + bh) * 4160 + 4096 + dc];
  }
  KVTx[(size_t)bh * 5120 + j] = (_Float16)s;
}

// ---------------------------------------------------------------------------
// attn: per (mtile, bh): att[m][e] = Z(m) * sum_d Q[m][d]*KV[d][e]
// B tile has 80 rows: 64 KVT rows + Ksum row (64) + 15 zero rows; the 5th
// n-fragment's column 0 yields the Z denominator per row via the same MFMA.
// ---------------------------------------------------------------------------
__global__ __launch_bounds__(256, 2)
void attn_kernel(const _Float16* __restrict__ Qp, const _Float16* __restrict__ KVTx,
                 _Float16* __restrict__ att) {
  const int mt = blockIdx.x;      // 0..31
  const int bh = blockIdx.y;      // 0..63
  const int b  = bh >> 4, h = bh & 15;
  const int tid = threadIdx.x;
  const int lane = tid & 63;
  const int w = tid >> 6;
  const size_t m0 = (size_t)b * 4096 + (size_t)mt * 128;

  __shared__ _Float16 As[128 * 64];
  __shared__ _Float16 Bs[80 * 64];

  // stage Q tile (128x64)
#pragma unroll
  for (int j = 0; j < 4; ++j) {
    int c    = tid + 256 * j;
    int row  = c >> 3;
    int col8 = (c & 7) << 3;
    int byte = row * 128 + (col8 << 1);
    byte ^= (row & 7) << 4;
    *(half8*)((char*)As + byte) =
        *(const half8*)(Qp + (m0 + row) * KDIM + h * 64 + col8);
  }
  // stage KVTx (80x64)
  for (int c = tid; c < 640; c += 256) {
    int row  = c >> 3;
    int col8 = (c & 7) << 3;
    int byte = row * 128 + (col8 << 1);
    byte ^= (row & 7) << 4;
    *(half8*)((char*)Bs + byte) = *(const half8*)(KVTx + (size_t)bh * 5120 + c * 8);
  }
  __syncthreads();

  f32x4 acc[2][5] = {};
  half8 afr[2][2], bfr[5][2];
#pragma unroll
  for (int m = 0; m < 2; ++m)
#pragma unroll
    for (int kk = 0; kk < 2; ++kk) {
      int row  = w * 32 + m * 16 + (lane & 15);
      int byte = row * 128 + ((lane >> 4) << 4) + kk * 64;
      byte ^= (row & 7) << 4;
      afr[m][kk] = *(const half8*)((const char*)As + byte);
    }
#pragma unroll
  for (int n = 0; n < 5; ++n)
#pragma unroll
    for (int kk = 0; kk < 2; ++kk) {
      int row  = n * 16 + (lane & 15);
      int byte = row * 128 + ((lane >> 4) << 4) + kk * 64;
      byte ^= (row & 7) << 4;
      bfr[n][kk] = *(const half8*)((const char*)Bs + byte);
    }
#pragma unroll
  for (int kk = 0; kk < 2; ++kk)
#pragma unroll
    for (int m = 0; m < 2; ++m)
#pragma unroll
      for (int n = 0; n < 5; ++n)
        acc[m][n] = __builtin_amdgcn_mfma_f32_16x16x32_f16(afr[m][kk], bfr[n][kk],
                                                           acc[m][n], 0, 0, 0);

#pragma unroll
  for (int m = 0; m < 2; ++m) {
#pragma unroll
    for (int i = 0; i < 4; ++i) {
      float dn = __shfl(acc[m][4][i], lane & 48);
      float z  = 1.f / (dn + 1e-6f);
      size_t row = m0 + w * 32 + m * 16 + ((lane >> 4) << 2) + i;
#pragma unroll
      for (int n = 0; n < 4; ++n) {
        att[row * NDIM + h * 64 + n * 16 + (lane & 15)] =
            (_Float16)(acc[m][n][i] * z);
      }
    }
  }
}

// ---------------------------------------------------------------------------
extern "C" void kernel_launch(void* const* d_in, const int* in_sizes, int n_in,
                              void* d_out, int out_size, void* d_ws, size_t ws_size,
                              hipStream_t stream) {
  const float* q  = (const float*)d_in[0];
  const float* k  = (const float*)d_in[1];
  const float* v  = (const float*)d_in[2];
  const float* wq = (const float*)d_in[3];
  const float* bq = (const float*)d_in[4];
  const float* wk = (const float*)d_in[5];
  const float* bk = (const float*)d_in[6];
  const float* wv = (const float*)d_in[7];
  const float* bv = (const float*)d_in[8];
  const float* wo = (const float*)d_in[9];
  const float* bo = (const float*)d_in[10];
  float* out = (float*)d_out;

  char* ws = (char*)d_ws;
  _Float16* Qp   = (_Float16*)(ws);                    // 33,554,432 B
  _Float16* Kp   = (_Float16*)(ws + 33554432);         // 33,554,432 B
  _Float16* Vp   = (_Float16*)(ws + 67108864);         // 33,554,432 B
  _Float16* Wh   = (_Float16*)(ws + 100663296);        //  2,097,152 B (reused 4x)
  float*    pKV  = (float*)(ws + 102760448);           //  8,519,680 B
  _Float16* KVTx = (_Float16*)(ws + 111280128);        //    655,360 B
  _Float16* att  = Kp;                                 // reuse Kp after KV built
  // fp16 X scratch lives in d_out (64 MB fp32, dead until final GEMM)
  _Float16* Xh   = (_Float16*)d_out;

  const int N8_BIG = MROWS * KDIM / 8;   // 2,097,152
  const int N8_W   = KDIM * KDIM / 8;    //   131,072

  dim3 gproj(MROWS / 128, NDIM / 128);

  // Q projection
  cvt_f32_to_f16<<<2048, 256, 0, stream>>>(q, Xh, N8_BIG);
  cvt_f32_to_f16<<<512, 256, 0, stream>>>(wq, Wh, N8_W);
  gemm_h<1, _Float16><<<gproj, 256, 0, stream>>>(Xh, Wh, bq, Qp);
  // K projection
  cvt_f32_to_f16<<<2048, 256, 0, stream>>>(k, Xh, N8_BIG);
  cvt_f32_to_f16<<<512, 256, 0, stream>>>(wk, Wh, N8_W);
  gemm_h<1, _Float16><<<gproj, 256, 0, stream>>>(Xh, Wh, bk, Kp);
  // V projection
  cvt_f32_to_f16<<<2048, 256, 0, stream>>>(v, Xh, N8_BIG);
  cvt_f32_to_f16<<<512, 256, 0, stream>>>(wv, Wh, N8_W);
  gemm_h<0, _Float16><<<gproj, 256, 0, stream>>>(Xh, Wh, bv, Vp);

  kv_partial<<<dim3(64, 8), 256, 0, stream>>>(Kp, Vp, pKV);
  kv_combine<<<1280, 256, 0, stream>>>(pKV, KVTx);

  attn_kernel<<<dim3(32, 64), 256, 0, stream>>>(Qp, KVTx, att);

  // output projection (writes d_out; Xh scratch is dead by now)
  cvt_f32_to_f16<<<512, 256, 0, stream>>>(wo, Wh, N8_W);
  gemm_h<0, float><<<gproj, 256, 0, stream>>>(att, Wh, bo, out);
}

// Round 3
// 280.747 us; speedup vs baseline: 2.0770x; 1.2287x over previous
//
#include <hip/hip_runtime.h>
#include <hip/hip_bf16.h>

typedef _Float16 half8 __attribute__((ext_vector_type(8)));
typedef _Float16 half4 __attribute__((ext_vector_type(4)));
typedef float f32x4 __attribute__((ext_vector_type(4)));

#define KDIM 1024
#define NDIM 1024
#define MROWS 16384   // B*L = 4*4096

#define GLD_LDS16(g, l)                                                  \
  __builtin_amdgcn_global_load_lds(                                      \
      (const __attribute__((address_space(1))) void*)(g),                \
      (__attribute__((address_space(3))) void*)(l), 16, 0, 0)

// ---------------------------------------------------------------------------
// fp32 -> fp16 convert, 8 elems/thread, grid-stride
// ---------------------------------------------------------------------------
__global__ __launch_bounds__(256)
void cvt_f32_to_f16(const float* __restrict__ src, _Float16* __restrict__ dst,
                    int n8) {
  for (int i = blockIdx.x * 256 + threadIdx.x; i < n8; i += gridDim.x * 256) {
    float4 f0 = ((const float4*)src)[2 * i];
    float4 f1 = ((const float4*)src)[2 * i + 1];
    half8 h;
    h[0] = (_Float16)f0.x; h[1] = (_Float16)f0.y;
    h[2] = (_Float16)f0.z; h[3] = (_Float16)f0.w;
    h[4] = (_Float16)f1.x; h[5] = (_Float16)f1.y;
    h[6] = (_Float16)f1.z; h[7] = (_Float16)f1.w;
    ((half8*)dst)[i] = h;
  }
}

// ---------------------------------------------------------------------------
// Y = act(X @ W^T + bias), all-fp16 inputs, m97 structure:
// 128x128 tile, BK=64, 4 waves (2x2 of 64x64), global_load_lds width=16,
// linear LDS dest + inverse-swizzled global source + XOR-swizzled ds_read
// (rule 21), mfma_f32_16x16x32_f16, fp32 accum.
// ACT: 0 = none, 1 = elu(x)+1
// TRANS: 0 = Y[row][col] natural; 1 = transposed fp16 per-head:
//   Y[(b*1024 + col)*4096 + l] with l = row&4095, b = row>>12 (packed half4)
// ---------------------------------------------------------------------------
template <int ACT, int TRANS, typename TOUT>
__global__ __launch_bounds__(256, 2)
void gemm_h(const _Float16* __restrict__ X, const _Float16* __restrict__ W,
            const float* __restrict__ bias, TOUT* __restrict__ Y) {
  constexpr int BM = 128, BN = 128, BK = 64;
  __shared__ _Float16 As[BM * BK];
  __shared__ _Float16 Bs[BN * BK];
  const int tid  = threadIdx.x;
  const int lane = tid & 63;
  const int w    = tid >> 6;
  const int wr   = (w >> 1) * 64;
  const int wc   = (w & 1) * 64;
  const int m0   = blockIdx.x * BM;
  const int n0   = blockIdx.y * BN;

  const int lr = lane >> 3;          // row within 8-row chunk == row&7
  const int ls = (lane & 7) ^ lr;    // inverse-swizzled 16B slot
  const _Float16* gA = X + (size_t)(m0 + w * 32 + lr) * KDIM + ls * 8;
  const _Float16* gB = W + (size_t)(n0 + w * 32 + lr) * KDIM + ls * 8;
  _Float16* ldsA = As + (w * 32) * BK;
  _Float16* ldsB = Bs + (w * 32) * BK;

  f32x4 acc[4][4] = {};

  for (int k0 = 0; k0 < KDIM; k0 += BK) {
    __syncthreads();
#pragma unroll
    for (int c = 0; c < 4; ++c) {
      GLD_LDS16(gA + k0 + (size_t)(c * 8) * KDIM, ldsA + c * 8 * BK);
      GLD_LDS16(gB + k0 + (size_t)(c * 8) * KDIM, ldsB + c * 8 * BK);
    }
    __syncthreads();   // drains vmcnt(0): LDS tiles ready

    half8 afr[4][2], bfr[4][2];
#pragma unroll
    for (int m = 0; m < 4; ++m)
#pragma unroll
      for (int kk = 0; kk < 2; ++kk) {
        int row  = wr + m * 16 + (lane & 15);
        int byte = row * 128 + ((lane >> 4) << 4) + kk * 64;
        byte ^= (row & 7) << 4;
        afr[m][kk] = *(const half8*)((const char*)As + byte);
      }
#pragma unroll
    for (int n = 0; n < 4; ++n)
#pragma unroll
      for (int kk = 0; kk < 2; ++kk) {
        int row  = wc + n * 16 + (lane & 15);
        int byte = row * 128 + ((lane >> 4) << 4) + kk * 64;
        byte ^= (row & 7) << 4;
        bfr[n][kk] = *(const half8*)((const char*)Bs + byte);
      }
#pragma unroll
    for (int kk = 0; kk < 2; ++kk)
#pragma unroll
      for (int m = 0; m < 4; ++m)
#pragma unroll
        for (int n = 0; n < 4; ++n)
          acc[m][n] = __builtin_amdgcn_mfma_f32_16x16x32_f16(afr[m][kk], bfr[n][kk],
                                                             acc[m][n], 0, 0, 0);
  }

  // epilogue: bias + activation + store
#pragma unroll
  for (int n = 0; n < 4; ++n) {
    int col  = n0 + wc + n * 16 + (lane & 15);
    float bv = bias[col];
#pragma unroll
    for (int m = 0; m < 4; ++m) {
      int r0 = m0 + wr + m * 16 + ((lane >> 4) << 2);
      if constexpr (TRANS) {
        int b  = r0 >> 12;
        int l0 = r0 & 4095;
        half4 hv;
#pragma unroll
        for (int i = 0; i < 4; ++i) {
          float v = acc[m][n][i] + bv;
          if constexpr (ACT == 1) v = (v > 0.f) ? (v + 1.f) : __expf(v);
          hv[i] = (_Float16)v;
        }
        *(half4*)((_Float16*)Y + ((size_t)(b * 1024 + col)) * 4096 + l0) = hv;
      } else {
#pragma unroll
        for (int i = 0; i < 4; ++i) {
          float v = acc[m][n][i] + bv;
          if constexpr (ACT == 1) v = (v > 0.f) ? (v + 1.f) : __expf(v);
          Y[(size_t)(r0 + i) * NDIM + col] = (TOUT)v;
        }
      }
    }
  }
}

// ---------------------------------------------------------------------------
// kv_mfma: per (bh, chunk): partial C'[e][d] = sum_l VT[e][l]*KT[d][l]
// over l in [ch*512, ch*512+512). A = VT rows (m=0..63) + synthesized
// ones-row (m-frag 4, row 64 -> Ksum) ; B = KT rows. Output fp16 partials
// pKV[(ch*64+bh)*5120 + row*64 + col], rows 0..79 (65..79 zero).
// ---------------------------------------------------------------------------
__global__ __launch_bounds__(256, 2)
void kv_mfma(const _Float16* __restrict__ KT, const _Float16* __restrict__ VT,
             _Float16* __restrict__ pKV) {
  const int bh = blockIdx.x;      // 0..63
  const int ch = blockIdx.y;      // 0..7
  const int tid  = threadIdx.x;
  const int lane = tid & 63;
  const int w    = tid >> 6;

  __shared__ _Float16 As[64 * 64];  // VT tile
  __shared__ _Float16 Bs[64 * 64];  // KT tile

  const int lr = lane >> 3;
  const int ls = (lane & 7) ^ lr;
  const size_t lbase = (size_t)ch * 512 + ls * 8;
  const _Float16* gA = VT + (size_t)(bh * 64 + w * 16 + lr) * 4096 + lbase;
  const _Float16* gB = KT + (size_t)(bh * 64 + w * 16 + lr) * 4096 + lbase;
  _Float16* ldsA = As + (w * 16) * 64;
  _Float16* ldsB = Bs + (w * 16) * 64;

  // ones-row A fragment (row 64 of the virtual 80-row A)
  half8 aones;
#pragma unroll
  for (int j = 0; j < 8; ++j) aones[j] = (lane & 15) == 0 ? (_Float16)1.0f : (_Float16)0.0f;

  f32x4 acc[5] = {};

  for (int k0 = 0; k0 < 512; k0 += 64) {
    __syncthreads();
#pragma unroll
    for (int c = 0; c < 2; ++c) {
      GLD_LDS16(gA + k0 + (size_t)(c * 8) * 4096, ldsA + c * 8 * 64);
      GLD_LDS16(gB + k0 + (size_t)(c * 8) * 4096, ldsB + c * 8 * 64);
    }
    __syncthreads();

    half8 afr[4][2], bfr[2];
#pragma unroll
    for (int m = 0; m < 4; ++m)
#pragma unroll
      for (int kk = 0; kk < 2; ++kk) {
        int row  = m * 16 + (lane & 15);
        int byte = row * 128 + ((lane >> 4) << 4) + kk * 64;
        byte ^= (row & 7) << 4;
        afr[m][kk] = *(const half8*)((const char*)As + byte);
      }
#pragma unroll
    for (int kk = 0; kk < 2; ++kk) {
      int row  = w * 16 + (lane & 15);
      int byte = row * 128 + ((lane >> 4) << 4) + kk * 64;
      byte ^= (row & 7) << 4;
      bfr[kk] = *(const half8*)((const char*)Bs + byte);
    }
#pragma unroll
    for (int kk = 0; kk < 2; ++kk) {
#pragma unroll
      for (int m = 0; m < 4; ++m)
        acc[m] = __builtin_amdgcn_mfma_f32_16x16x32_f16(afr[m][kk], bfr[kk],
                                                        acc[m], 0, 0, 0);
      acc[4] = __builtin_amdgcn_mfma_f32_16x16x32_f16(aones, bfr[kk],
                                                      acc[4], 0, 0, 0);
    }
  }

  _Float16* outp = pKV + ((size_t)ch * 64 + bh) * 5120;
  const int col = w * 16 + (lane & 15);
#pragma unroll
  for (int m = 0; m < 5; ++m) {
#pragma unroll
    for (int i = 0; i < 4; ++i) {
      int row = m * 16 + ((lane >> 4) << 2) + i;
      outp[row * 64 + col] = (_Float16)acc[m][i];
    }
  }
}

// ---------------------------------------------------------------------------
// Combine 8 fp16 partials -> KVTx fp16 [64 bh][80 rows][64 cols]
// ---------------------------------------------------------------------------
__global__ __launch_bounds__(256)
void kv_combine(const _Float16* __restrict__ pKV, _Float16* __restrict__ KVTx) {
  int g = blockIdx.x * 256 + threadIdx.x;   // 0..327679
  int bh = g / 5120;
  int j  = g - bh * 5120;
  float s = 0.f;
#pragma unroll
  for (int ch = 0; ch < 8; ++ch)
    s += (float)pKV[((size_t)ch * 64 + bh) * 5120 + j];
  KVTx[(size_t)bh * 5120 + j] = (_Float16)s;
}

// ---------------------------------------------------------------------------
// attn: per (mtile, bh): att[m][e] = Z(m) * sum_d Q[m][d]*KV[d][e]
// B tile has 80 rows: 64 KVT rows + Ksum row (64) + 15 zero rows; the 5th
// n-fragment's column 0 yields the Z denominator per row via the same MFMA.
// ---------------------------------------------------------------------------
__global__ __launch_bounds__(256, 2)
void attn_kernel(const _Float16* __restrict__ Qp, const _Float16* __restrict__ KVTx,
                 _Float16* __restrict__ att) {
  const int mt = blockIdx.x;      // 0..31
  const int bh = blockIdx.y;      // 0..63
  const int b  = bh >> 4, h = bh & 15;
  const int tid = threadIdx.x;
  const int lane = tid & 63;
  const int w = tid >> 6;
  const size_t m0 = (size_t)b * 4096 + (size_t)mt * 128;

  __shared__ _Float16 As[128 * 64];
  __shared__ _Float16 Bs[80 * 64];

  // stage Q tile (128x64)
#pragma unroll
  for (int j = 0; j < 4; ++j) {
    int c    = tid + 256 * j;
    int row  = c >> 3;
    int col8 = (c & 7) << 3;
    int byte = row * 128 + (col8 << 1);
    byte ^= (row & 7) << 4;
    *(half8*)((char*)As + byte) =
        *(const half8*)(Qp + (m0 + row) * KDIM + h * 64 + col8);
  }
  // stage KVTx (80x64)
  for (int c = tid; c < 640; c += 256) {
    int row  = c >> 3;
    int col8 = (c & 7) << 3;
    int byte = row * 128 + (col8 << 1);
    byte ^= (row & 7) << 4;
    *(half8*)((char*)Bs + byte) = *(const half8*)(KVTx + (size_t)bh * 5120 + c * 8);
  }
  __syncthreads();

  f32x4 acc[2][5] = {};
  half8 afr[2][2], bfr[5][2];
#pragma unroll
  for (int m = 0; m < 2; ++m)
#pragma unroll
    for (int kk = 0; kk < 2; ++kk) {
      int row  = w * 32 + m * 16 + (lane & 15);
      int byte = row * 128 + ((lane >> 4) << 4) + kk * 64;
      byte ^= (row & 7) << 4;
      afr[m][kk] = *(const half8*)((const char*)As + byte);
    }
#pragma unroll
  for (int n = 0; n < 5; ++n)
#pragma unroll
    for (int kk = 0; kk < 2; ++kk) {
      int row  = n * 16 + (lane & 15);
      int byte = row * 128 + ((lane >> 4) << 4) + kk * 64;
      byte ^= (row & 7) << 4;
      bfr[n][kk] = *(const half8*)((const char*)Bs + byte);
    }
#pragma unroll
  for (int kk = 0; kk < 2; ++kk)
#pragma unroll
    for (int m = 0; m < 2; ++m)
#pragma unroll
      for (int n = 0; n < 5; ++n)
        acc[m][n] = __builtin_amdgcn_mfma_f32_16x16x32_f16(afr[m][kk], bfr[n][kk],
                                                           acc[m][n], 0, 0, 0);

#pragma unroll
  for (int m = 0; m < 2; ++m) {
#pragma unroll
    for (int i = 0; i < 4; ++i) {
      float dn = __shfl(acc[m][4][i], lane & 48);
      float z  = 1.f / (dn + 1e-6f);
      size_t row = m0 + w * 32 + m * 16 + ((lane >> 4) << 2) + i;
#pragma unroll
      for (int n = 0; n < 4; ++n) {
        att[row * NDIM + h * 64 + n * 16 + (lane & 15)] =
            (_Float16)(acc[m][n][i] * z);
      }
    }
  }
}

// ---------------------------------------------------------------------------
extern "C" void kernel_launch(void* const* d_in, const int* in_sizes, int n_in,
                              void* d_out, int out_size, void* d_ws, size_t ws_size,
                              hipStream_t stream) {
  const float* q  = (const float*)d_in[0];
  const float* k  = (const float*)d_in[1];
  const float* v  = (const float*)d_in[2];
  const float* wq = (const float*)d_in[3];
  const float* bq = (const float*)d_in[4];
  const float* wk = (const float*)d_in[5];
  const float* bk = (const float*)d_in[6];
  const float* wv = (const float*)d_in[7];
  const float* bv = (const float*)d_in[8];
  const float* wo = (const float*)d_in[9];
  const float* bo = (const float*)d_in[10];
  float* out = (float*)d_out;

  char* ws = (char*)d_ws;
  _Float16* Qp   = (_Float16*)(ws);                    // 33,554,432 B
  _Float16* KT   = (_Float16*)(ws + 33554432);         // 33,554,432 B (att aliases)
  _Float16* VT   = (_Float16*)(ws + 67108864);         // 33,554,432 B
  _Float16* Wh   = (_Float16*)(ws + 100663296);        //  2,097,152 B (reused 4x)
  _Float16* pKVh = (_Float16*)(ws + 102760448);        //  5,242,880 B
  _Float16* KVTx = (_Float16*)(ws + 108003328);        //    655,360 B
  _Float16* att  = KT;                                 // reuse KT after KV built
  _Float16* Xh   = (_Float16*)d_out;                   // fp16 X scratch in d_out

  const int N8_BIG = MROWS * KDIM / 8;   // 2,097,152
  const int N8_W   = KDIM * KDIM / 8;    //   131,072

  dim3 gproj(MROWS / 128, NDIM / 128);

  // Q projection (natural layout)
  cvt_f32_to_f16<<<2048, 256, 0, stream>>>(q, Xh, N8_BIG);
  cvt_f32_to_f16<<<512, 256, 0, stream>>>(wq, Wh, N8_W);
  gemm_h<1, 0, _Float16><<<gproj, 256, 0, stream>>>(Xh, Wh, bq, Qp);
  // K projection (transposed per-head: KT[bh][d][l])
  cvt_f32_to_f16<<<2048, 256, 0, stream>>>(k, Xh, N8_BIG);
  cvt_f32_to_f16<<<512, 256, 0, stream>>>(wk, Wh, N8_W);
  gemm_h<1, 1, _Float16><<<gproj, 256, 0, stream>>>(Xh, Wh, bk, KT);
  // V projection (transposed per-head: VT[bh][e][l])
  cvt_f32_to_f16<<<2048, 256, 0, stream>>>(v, Xh, N8_BIG);
  cvt_f32_to_f16<<<512, 256, 0, stream>>>(wv, Wh, N8_W);
  gemm_h<0, 1, _Float16><<<gproj, 256, 0, stream>>>(Xh, Wh, bv, VT);

  kv_mfma<<<dim3(64, 8), 256, 0, stream>>>(KT, VT, pKVh);
  kv_combine<<<1280, 256, 0, stream>>>(pKVh, KVTx);

  attn_kernel<<<dim3(32, 64), 256, 0, stream>>>(Qp, KVTx, att);

  // output projection (writes d_out; Xh scratch is dead by now)
  cvt_f32_to_f16<<<512, 256, 0, stream>>>(wo, Wh, N8_W);
  gemm_h<0, 0, float><<<gproj, 256, 0, stream>>>(att, Wh, bo, out);
}

// Round 4
// 273.436 us; speedup vs baseline: 2.1325x; 1.0267x over previous
//
#include <hip/hip_runtime.h>
#include <hip/hip_bf16.h>

typedef _Float16 half8 __attribute__((ext_vector_type(8)));
typedef _Float16 half4 __attribute__((ext_vector_type(4)));
typedef float f32x4 __attribute__((ext_vector_type(4)));

#define KDIM 1024
#define NDIM 1024
#define MROWS 16384   // B*L = 4*4096

#define GLD_LDS16(g, l)                                                  \
  __builtin_amdgcn_global_load_lds(                                      \
      (const __attribute__((address_space(1))) void*)(g),                \
      (__attribute__((address_space(3))) void*)(l), 16, 0, 0)

// ---------------------------------------------------------------------------
// fp32 -> fp16 convert, 8 elems/thread, grid-stride
// ---------------------------------------------------------------------------
__global__ __launch_bounds__(256)
void cvt_f32_to_f16(const float* __restrict__ src, _Float16* __restrict__ dst,
                    int n8) {
  for (int i = blockIdx.x * 256 + threadIdx.x; i < n8; i += gridDim.x * 256) {
    float4 f0 = ((const float4*)src)[2 * i];
    float4 f1 = ((const float4*)src)[2 * i + 1];
    half8 h;
    h[0] = (_Float16)f0.x; h[1] = (_Float16)f0.y;
    h[2] = (_Float16)f0.z; h[3] = (_Float16)f0.w;
    h[4] = (_Float16)f1.x; h[5] = (_Float16)f1.y;
    h[6] = (_Float16)f1.z; h[7] = (_Float16)f1.w;
    ((half8*)dst)[i] = h;
  }
}

// ---------------------------------------------------------------------------
// Deep-pipelined GEMM: Y = act(X @ W^T + bias), fp16 in, fp32 accum.
// Tile 256x128, BK=64, 8 waves (4M x 2N, 64x64 per wave).
// Triple-buffered LDS (144 KB), staging 2 K-tiles ahead via
// global_load_lds(16B), counted s_waitcnt vmcnt(6) + raw s_barrier —
// never vmcnt(0) in the main loop (T3+T4). Rule-21 swizzle:
// linear LDS dest, inverse-swizzled global source, XOR-swizzled ds_read.
// Safety: one barrier per K-tile; a wave's tile-t ds_reads are consumed by
// its MFMAs before the trailing barrier, so stage(t+2) into buf (t-1)%3
// (issued only after that barrier by any wave) cannot race readers.
// ACT: 0 = none, 1 = elu(x)+1
// TRANS: 0 = Y[row][col] natural; 1 = per-head transposed fp16:
//   Y[(b*1024 + col)*4096 + (row&4095)], b = row>>12 (packed half4)
// ---------------------------------------------------------------------------
template <int ACT, int TRANS, typename TOUT>
__global__ __launch_bounds__(512, 2)
void gemm_big(const _Float16* __restrict__ X, const _Float16* __restrict__ W,
              const float* __restrict__ bias, TOUT* __restrict__ Y) {
  constexpr int BM = 256, BN = 128, BK = 64;
  __shared__ _Float16 As[3 * BM * BK];   // 96 KB
  __shared__ _Float16 Bs[3 * BN * BK];   // 48 KB

  const int tid  = threadIdx.x;
  const int lane = tid & 63;
  const int w    = tid >> 6;          // 0..7
  const int wm   = w >> 1;            // 0..3  -> rows wm*64
  const int wn   = w & 1;             // 0..1  -> cols wn*64

  // XCD-aware bijective swizzle (512 blocks, 8 XCDs -> 64 each)
  const int bid = blockIdx.x;
  const int wid = (bid & 7) * 64 + (bid >> 3);
  const int m0  = (wid >> 3) * BM;    // 64 m-blocks
  const int n0  = (wid & 7) * BN;     // 8 n-blocks

  const int lr = lane >> 3;           // row within 8-row group
  const int ls = (lane & 7) ^ lr;     // inverse-swizzled 16B slot

#define STAGE_TILE(kt, bidx)                                                  \
  {                                                                           \
    const int k0s = (kt) * BK;                                                \
    _Float16* la = As + (bidx) * (BM * BK) + w * 512;                         \
    _Float16* lb = Bs + (bidx) * (BN * BK) + w * 512;                         \
    _Pragma("unroll")                                                         \
    for (int j = 0; j < 4; ++j)                                               \
      GLD_LDS16(X + (size_t)(m0 + w * 8 + 64 * j + lr) * KDIM + k0s + ls * 8, \
                la + 4096 * j);                                               \
    _Pragma("unroll")                                                         \
    for (int j = 0; j < 2; ++j)                                               \
      GLD_LDS16(W + (size_t)(n0 + w * 8 + 64 * j + lr) * KDIM + k0s + ls * 8, \
                lb + 4096 * j);                                               \
  }

  f32x4 acc[4][4] = {};

  // prologue: stage tiles 0,1 into buffers 0,1 (12 loads in flight)
  STAGE_TILE(0, 0);
  STAGE_TILE(1, 1);
  asm volatile("s_waitcnt vmcnt(6)" ::: "memory");  // tile 0 landed (own)
  asm volatile("s_barrier" ::: "memory");           // all waves' tile 0 landed

  int bc = 0;
  for (int t = 0; t < 16; ++t) {
    int bs = bc + 2; if (bs >= 3) bs -= 3;
    const char* Ab = (const char*)As + bc * (BM * BK * 2);
    const char* Bb = (const char*)Bs + bc * (BN * BK * 2);

    // fragment ds_reads (buffer bc)
    half8 afr[4][2], bfr[4][2];
#pragma unroll
    for (int mi = 0; mi < 4; ++mi)
#pragma unroll
      for (int kk = 0; kk < 2; ++kk) {
        int row  = wm * 64 + mi * 16 + (lane & 15);
        int byte = row * 128 + ((lane >> 4) << 4) + kk * 64;
        byte ^= (row & 7) << 4;
        afr[mi][kk] = *(const half8*)(Ab + byte);
      }
#pragma unroll
    for (int ni = 0; ni < 4; ++ni)
#pragma unroll
      for (int kk = 0; kk < 2; ++kk) {
        int row  = wn * 64 + ni * 16 + (lane & 15);
        int byte = row * 128 + ((lane >> 4) << 4) + kk * 64;
        byte ^= (row & 7) << 4;
        bfr[ni][kk] = *(const half8*)(Bb + byte);
      }

    // prefetch tile t+2 (in flight across the next barrier)
    if (t < 14) STAGE_TILE(t + 2, bs);

    __builtin_amdgcn_s_setprio(1);
#pragma unroll
    for (int kk = 0; kk < 2; ++kk)
#pragma unroll
      for (int mi = 0; mi < 4; ++mi)
#pragma unroll
        for (int ni = 0; ni < 4; ++ni)
          acc[mi][ni] = __builtin_amdgcn_mfma_f32_16x16x32_f16(
              afr[mi][kk], bfr[ni][kk], acc[mi][ni], 0, 0, 0);
    __builtin_amdgcn_s_setprio(0);

    if (t < 15) {
      asm volatile("s_waitcnt vmcnt(6)" ::: "memory");  // tile t+1 landed (own)
      asm volatile("s_barrier" ::: "memory");           // all waves ready
    }
    ++bc; if (bc == 3) bc = 0;
  }
#undef STAGE_TILE

  // epilogue: bias + activation + store
#pragma unroll
  for (int ni = 0; ni < 4; ++ni) {
    int col  = n0 + wn * 64 + ni * 16 + (lane & 15);
    float bv = bias[col];
#pragma unroll
    for (int mi = 0; mi < 4; ++mi) {
      int r0 = m0 + wm * 64 + mi * 16 + ((lane >> 4) << 2);
      if constexpr (TRANS) {
        int b  = r0 >> 12;
        int l0 = r0 & 4095;
        half4 hv;
#pragma unroll
        for (int i = 0; i < 4; ++i) {
          float v = acc[mi][ni][i] + bv;
          if constexpr (ACT == 1) v = (v > 0.f) ? (v + 1.f) : __expf(v);
          hv[i] = (_Float16)v;
        }
        *(half4*)((_Float16*)Y + ((size_t)(b * 1024 + col)) * 4096 + l0) = hv;
      } else {
#pragma unroll
        for (int i = 0; i < 4; ++i) {
          float v = acc[mi][ni][i] + bv;
          if constexpr (ACT == 1) v = (v > 0.f) ? (v + 1.f) : __expf(v);
          Y[(size_t)(r0 + i) * NDIM + col] = (TOUT)v;
        }
      }
    }
  }
}

// ---------------------------------------------------------------------------
// kv_mfma: per (bh, chunk): partial C'[e][d] = sum_l VT[e][l]*KT[d][l]
// over l in [ch*512, ch*512+512). A = VT rows (m=0..63) + synthesized
// ones-row (m-frag 4, row 64 -> Ksum) ; B = KT rows. Output fp16 partials
// pKV[(ch*64+bh)*5120 + row*64 + col], rows 0..79 (65..79 zero).
// ---------------------------------------------------------------------------
__global__ __launch_bounds__(256, 2)
void kv_mfma(const _Float16* __restrict__ KT, const _Float16* __restrict__ VT,
             _Float16* __restrict__ pKV) {
  const int bh = blockIdx.x;      // 0..63
  const int ch = blockIdx.y;      // 0..7
  const int tid  = threadIdx.x;
  const int lane = tid & 63;
  const int w    = tid >> 6;

  __shared__ _Float16 As[64 * 64];  // VT tile
  __shared__ _Float16 Bs[64 * 64];  // KT tile

  const int lr = lane >> 3;
  const int ls = (lane & 7) ^ lr;
  const size_t lbase = (size_t)ch * 512 + ls * 8;
  const _Float16* gA = VT + (size_t)(bh * 64 + w * 16 + lr) * 4096 + lbase;
  const _Float16* gB = KT + (size_t)(bh * 64 + w * 16 + lr) * 4096 + lbase;
  _Float16* ldsA = As + (w * 16) * 64;
  _Float16* ldsB = Bs + (w * 16) * 64;

  half8 aones;
#pragma unroll
  for (int j = 0; j < 8; ++j) aones[j] = (lane & 15) == 0 ? (_Float16)1.0f : (_Float16)0.0f;

  f32x4 acc[5] = {};

  for (int k0 = 0; k0 < 512; k0 += 64) {
    __syncthreads();
#pragma unroll
    for (int c = 0; c < 2; ++c) {
      GLD_LDS16(gA + k0 + (size_t)(c * 8) * 4096, ldsA + c * 8 * 64);
      GLD_LDS16(gB + k0 + (size_t)(c * 8) * 4096, ldsB + c * 8 * 64);
    }
    __syncthreads();

    half8 afr[4][2], bfr[2];
#pragma unroll
    for (int m = 0; m < 4; ++m)
#pragma unroll
      for (int kk = 0; kk < 2; ++kk) {
        int row  = m * 16 + (lane & 15);
        int byte = row * 128 + ((lane >> 4) << 4) + kk * 64;
        byte ^= (row & 7) << 4;
        afr[m][kk] = *(const half8*)((const char*)As + byte);
      }
#pragma unroll
    for (int kk = 0; kk < 2; ++kk) {
      int row  = w * 16 + (lane & 15);
      int byte = row * 128 + ((lane >> 4) << 4) + kk * 64;
      byte ^= (row & 7) << 4;
      bfr[kk] = *(const half8*)((const char*)Bs + byte);
    }
#pragma unroll
    for (int kk = 0; kk < 2; ++kk) {
#pragma unroll
      for (int m = 0; m < 4; ++m)
        acc[m] = __builtin_amdgcn_mfma_f32_16x16x32_f16(afr[m][kk], bfr[kk],
                                                        acc[m], 0, 0, 0);
      acc[4] = __builtin_amdgcn_mfma_f32_16x16x32_f16(aones, bfr[kk],
                                                      acc[4], 0, 0, 0);
    }
  }

  _Float16* outp = pKV + ((size_t)ch * 64 + bh) * 5120;
  const int col = w * 16 + (lane & 15);
#pragma unroll
  for (int m = 0; m < 5; ++m) {
#pragma unroll
    for (int i = 0; i < 4; ++i) {
      int row = m * 16 + ((lane >> 4) << 2) + i;
      outp[row * 64 + col] = (_Float16)acc[m][i];
    }
  }
}

// ---------------------------------------------------------------------------
// Combine 8 fp16 partials -> KVTx fp16 [64 bh][80 rows][64 cols]
// ---------------------------------------------------------------------------
__global__ __launch_bounds__(256)
void kv_combine(const _Float16* __restrict__ pKV, _Float16* __restrict__ KVTx) {
  int g = blockIdx.x * 256 + threadIdx.x;   // 0..327679
  int bh = g / 5120;
  int j  = g - bh * 5120;
  float s = 0.f;
#pragma unroll
  for (int ch = 0; ch < 8; ++ch)
    s += (float)pKV[((size_t)ch * 64 + bh) * 5120 + j];
  KVTx[(size_t)bh * 5120 + j] = (_Float16)s;
}

// ---------------------------------------------------------------------------
// attn: per (mtile, bh): att[m][e] = Z(m) * sum_d Q[m][d]*KV[d][e]
// B tile has 80 rows: 64 KVT rows + Ksum row (64) + 15 zero rows; the 5th
// n-fragment's column 0 yields the Z denominator per row via the same MFMA.
// ---------------------------------------------------------------------------
__global__ __launch_bounds__(256, 2)
void attn_kernel(const _Float16* __restrict__ Qp, const _Float16* __restrict__ KVTx,
                 _Float16* __restrict__ att) {
  const int mt = blockIdx.x;      // 0..31
  const int bh = blockIdx.y;      // 0..63
  const int b  = bh >> 4, h = bh & 15;
  const int tid = threadIdx.x;
  const int lane = tid & 63;
  const int w = tid >> 6;
  const size_t m0 = (size_t)b * 4096 + (size_t)mt * 128;

  __shared__ _Float16 As[128 * 64];
  __shared__ _Float16 Bs[80 * 64];

#pragma unroll
  for (int j = 0; j < 4; ++j) {
    int c    = tid + 256 * j;
    int row  = c >> 3;
    int col8 = (c & 7) << 3;
    int byte = row * 128 + (col8 << 1);
    byte ^= (row & 7) << 4;
    *(half8*)((char*)As + byte) =
        *(const half8*)(Qp + (m0 + row) * KDIM + h * 64 + col8);
  }
  for (int c = tid; c < 640; c += 256) {
    int row  = c >> 3;
    int col8 = (c & 7) << 3;
    int byte = row * 128 + (col8 << 1);
    byte ^= (row & 7) << 4;
    *(half8*)((char*)Bs + byte) = *(const half8*)(KVTx + (size_t)bh * 5120 + c * 8);
  }
  __syncthreads();

  f32x4 acc[2][5] = {};
  half8 afr[2][2], bfr[5][2];
#pragma unroll
  for (int m = 0; m < 2; ++m)
#pragma unroll
    for (int kk = 0; kk < 2; ++kk) {
      int row  = w * 32 + m * 16 + (lane & 15);
      int byte = row * 128 + ((lane >> 4) << 4) + kk * 64;
      byte ^= (row & 7) << 4;
      afr[m][kk] = *(const half8*)((const char*)As + byte);
    }
#pragma unroll
  for (int n = 0; n < 5; ++n)
#pragma unroll
    for (int kk = 0; kk < 2; ++kk) {
      int row  = n * 16 + (lane & 15);
      int byte = row * 128 + ((lane >> 4) << 4) + kk * 64;
      byte ^= (row & 7) << 4;
      bfr[n][kk] = *(const half8*)((const char*)Bs + byte);
    }
#pragma unroll
  for (int kk = 0; kk < 2; ++kk)
#pragma unroll
    for (int m = 0; m < 2; ++m)
#pragma unroll
      for (int n = 0; n < 5; ++n)
        acc[m][n] = __builtin_amdgcn_mfma_f32_16x16x32_f16(afr[m][kk], bfr[n][kk],
                                                           acc[m][n], 0, 0, 0);

#pragma unroll
  for (int m = 0; m < 2; ++m) {
#pragma unroll
    for (int i = 0; i < 4; ++i) {
      float dn = __shfl(acc[m][4][i], lane & 48);
      float z  = 1.f / (dn + 1e-6f);
      size_t row = m0 + w * 32 + m * 16 + ((lane >> 4) << 2) + i;
#pragma unroll
      for (int n = 0; n < 4; ++n) {
        att[row * NDIM + h * 64 + n * 16 + (lane & 15)] =
            (_Float16)(acc[m][n][i] * z);
      }
    }
  }
}

// ---------------------------------------------------------------------------
extern "C" void kernel_launch(void* const* d_in, const int* in_sizes, int n_in,
                              void* d_out, int out_size, void* d_ws, size_t ws_size,
                              hipStream_t stream) {
  const float* q  = (const float*)d_in[0];
  const float* k  = (const float*)d_in[1];
  const float* v  = (const float*)d_in[2];
  const float* wq = (const float*)d_in[3];
  const float* bq = (const float*)d_in[4];
  const float* wk = (const float*)d_in[5];
  const float* bk = (const float*)d_in[6];
  const float* wv = (const float*)d_in[7];
  const float* bv = (const float*)d_in[8];
  const float* wo = (const float*)d_in[9];
  const float* bo = (const float*)d_in[10];
  float* out = (float*)d_out;

  char* ws = (char*)d_ws;
  _Float16* Qp   = (_Float16*)(ws);                    // 33,554,432 B
  _Float16* KT   = (_Float16*)(ws + 33554432);         // 33,554,432 B (att aliases)
  _Float16* VT   = (_Float16*)(ws + 67108864);         // 33,554,432 B
  _Float16* Wh   = (_Float16*)(ws + 100663296);        //  2,097,152 B (reused 4x)
  _Float16* pKVh = (_Float16*)(ws + 102760448);        //  5,242,880 B
  _Float16* KVTx = (_Float16*)(ws + 108003328);        //    655,360 B
  _Float16* att  = KT;                                 // reuse KT after KV built
  _Float16* Xh   = (_Float16*)d_out;                   // fp16 X scratch in d_out

  const int N8_BIG = MROWS * KDIM / 8;   // 2,097,152
  const int N8_W   = KDIM * KDIM / 8;    //   131,072

  const int GBLK = (MROWS / 256) * (NDIM / 128);   // 512 blocks

  // Q projection (natural layout)
  cvt_f32_to_f16<<<2048, 256, 0, stream>>>(q, Xh, N8_BIG);
  cvt_f32_to_f16<<<512, 256, 0, stream>>>(wq, Wh, N8_W);
  gemm_big<1, 0, _Float16><<<GBLK, 512, 0, stream>>>(Xh, Wh, bq, Qp);
  // K projection (transposed per-head: KT[bh][d][l])
  cvt_f32_to_f16<<<2048, 256, 0, stream>>>(k, Xh, N8_BIG);
  cvt_f32_to_f16<<<512, 256, 0, stream>>>(wk, Wh, N8_W);
  gemm_big<1, 1, _Float16><<<GBLK, 512, 0, stream>>>(Xh, Wh, bk, KT);
  // V projection (transposed per-head: VT[bh][e][l])
  cvt_f32_to_f16<<<2048, 256, 0, stream>>>(v, Xh, N8_BIG);
  cvt_f32_to_f16<<<512, 256, 0, stream>>>(wv, Wh, N8_W);
  gemm_big<0, 1, _Float16><<<GBLK, 512, 0, stream>>>(Xh, Wh, bv, VT);

  kv_mfma<<<dim3(64, 8), 256, 0, stream>>>(KT, VT, pKVh);
  kv_combine<<<1280, 256, 0, stream>>>(pKVh, KVTx);

  attn_kernel<<<dim3(32, 64), 256, 0, stream>>>(Qp, KVTx, att);

  // output projection (writes d_out; Xh scratch is dead by now)
  cvt_f32_to_f16<<<512, 256, 0, stream>>>(wo, Wh, N8_W);
  gemm_big<0, 0, float><<<GBLK, 512, 0, stream>>>(att, Wh, bo, out);
}

// Round 5
// 272.785 us; speedup vs baseline: 2.1376x; 1.0024x over previous
//
#include <hip/hip_runtime.h>
#include <hip/hip_bf16.h>

typedef _Float16 half8 __attribute__((ext_vector_type(8)));
typedef _Float16 half4 __attribute__((ext_vector_type(4)));
typedef float f32x4 __attribute__((ext_vector_type(4)));

#define KDIM 1024
#define NDIM 1024
#define MROWS 16384   // B*L = 4*4096

#define GLD_LDS16(g, l)                                                  \
  __builtin_amdgcn_global_load_lds(                                      \
      (const __attribute__((address_space(1))) void*)(g),                \
      (__attribute__((address_space(3))) void*)(l), 16, 0, 0)

#define SBAR asm volatile("s_barrier" ::: "memory")

// ---------------------------------------------------------------------------
// fp32 -> fp16 convert, 8 elems/thread, grid-stride
// ---------------------------------------------------------------------------
__global__ __launch_bounds__(256)
void cvt_f32_to_f16(const float* __restrict__ src, _Float16* __restrict__ dst,
                    int n8) {
  for (int i = blockIdx.x * 256 + threadIdx.x; i < n8; i += gridDim.x * 256) {
    float4 f0 = ((const float4*)src)[2 * i];
    float4 f1 = ((const float4*)src)[2 * i + 1];
    half8 h;
    h[0] = (_Float16)f0.x; h[1] = (_Float16)f0.y;
    h[2] = (_Float16)f0.z; h[3] = (_Float16)f0.w;
    h[4] = (_Float16)f1.x; h[5] = (_Float16)f1.y;
    h[6] = (_Float16)f1.z; h[7] = (_Float16)f1.w;
    ((half8*)dst)[i] = h;
  }
}

// ---------------------------------------------------------------------------
// 8-phase GEMM (T2+T3+T4+T5): Y = act(X @ W^T + bias), fp16 in, fp32 accum.
// BM=BN=256, BK=64, 8 waves (2M x 4N; per-wave 128x64 = 8x4 frags).
// LDS = 2 dbuf x 2 K-halves x 256x32 x {A,B} = 128 KB.
// Phase (mh,kh): 8 ds_read_b128 + 1 half-stage (2 global_load_lds) ->
// barrier -> 16 MFMA (setprio) -> counted vmcnt at P1/P3 -> barrier.
// Stage targets: P0/P1 -> next tile's Kh1 (other dbuf, retired last tile);
// P2/P3 -> tile+2's Kh0 (this dbuf, retired at P1). Never vmcnt(0) in
// steady state: vmcnt(8) twice per K-tile (12 loads in flight).
// Swizzle: rows are 64B; read slot ^= (row>>1)&3, realized via
// inverse-permuted global source + permuted ds_read (rule 21).
// ACT: 0 = none, 1 = elu(x)+1
// TRANS: 0 = natural; 1 = per-head transposed fp16 (packed half4):
//   Y[(b*1024 + col)*4096 + (row&4095)], b = row>>12
// ---------------------------------------------------------------------------
template <int ACT, int TRANS, typename TOUT>
__global__ __launch_bounds__(512, 2)
void gemm_8p(const _Float16* __restrict__ X, const _Float16* __restrict__ W,
             const float* __restrict__ bias, TOUT* __restrict__ Y) {
  __shared__ _Float16 As[2 * 2 * 8192];   // 64 KB: [dbuf][kh][256*32]
  __shared__ _Float16 Bs[2 * 2 * 8192];   // 64 KB

  const int tid  = threadIdx.x;
  const int lane = tid & 63;
  const int w    = tid >> 6;      // 0..7
  const int wm   = w >> 2;        // 0..1 -> rows wm*128
  const int wn   = w & 3;         // 0..3 -> cols wn*64

  // XCD-aware bijective swizzle (256 blocks, 8 XCDs -> 32 each; same-m
  // neighbors share A panels within an XCD)
  const int bid = blockIdx.x;
  const int wid = (bid & 7) * 32 + (bid >> 3);
  const int m0  = (wid >> 2) * 256;
  const int n0  = (wid & 3) * 256;

  // staging geometry: round j in {0,1}: row = j*128 + w*16 + (lane>>2),
  // LDS 16B-slot = lane&3; global col-slot = (lane&3) ^ ((row>>1)&3)
  //   where (row>>1)&3 == (lane>>3)&3 for this row pattern.
  const int srow = w * 16 + (lane >> 2);
  const int ssl  = (lane & 3) ^ ((lane >> 3) & 3);
  const _Float16* gA = X + (size_t)(m0 + srow) * KDIM + ssl * 8;
  const _Float16* gB = W + (size_t)(n0 + srow) * KDIM + ssl * 8;
  _Float16* lA = As + (size_t)(w * 64 + lane) * 8;   // + j*4096 per round
  _Float16* lB = Bs + (size_t)(w * 64 + lane) * 8;
  // read swizzle byte offset: slot = (lane>>4) ^ ((row>>1)&3); for read rows
  // (row>>1)&3 == (lane>>1)&3 -> per-thread constant
  const int rsl = ((lane >> 4) ^ ((lane >> 1) & 3)) << 4;

  f32x4 acc[8][4] = {};

#define STAGE(GP, LP, Tt, KH)                                              \
  {                                                                        \
    _Pragma("unroll")                                                      \
    for (int j = 0; j < 2; ++j)                                            \
      GLD_LDS16(GP + (size_t)j * 128 * KDIM + (Tt) * 64 + (KH) * 32,       \
                LP + ((Tt) & 1) * 16384 + (KH) * 8192 + j * 4096);         \
  }

#define PHASE(MH, KH, STG, WEND)                                           \
  {                                                                        \
    const char* Ab = (const char*)As + d * 32768 + (KH) * 16384;           \
    const char* Bb = (const char*)Bs + d * 32768 + (KH) * 16384;           \
    half8 afr[4], bfr[4];                                                  \
    _Pragma("unroll")                                                      \
    for (int mi = 0; mi < 4; ++mi) {                                       \
      int r = wm * 128 + (MH) * 64 + mi * 16 + (lane & 15);                \
      afr[mi] = *(const half8*)(Ab + r * 64 + rsl);                        \
    }                                                                      \
    _Pragma("unroll")                                                      \
    for (int ni = 0; ni < 4; ++ni) {                                       \
      int r = wn * 64 + ni * 16 + (lane & 15);                             \
      bfr[ni] = *(const half8*)(Bb + r * 64 + rsl);                        \
    }                                                                      \
    STG;                                                                   \
    SBAR;                                                                  \
    __builtin_amdgcn_s_setprio(1);                                         \
    _Pragma("unroll")                                                      \
    for (int mi = 0; mi < 4; ++mi)                                         \
      _Pragma("unroll")                                                    \
      for (int ni = 0; ni < 4; ++ni)                                       \
        acc[(MH) * 4 + mi][ni] = __builtin_amdgcn_mfma_f32_16x16x32_f16(   \
            afr[mi], bfr[ni], acc[(MH) * 4 + mi][ni], 0, 0, 0);            \
    __builtin_amdgcn_s_setprio(0);                                         \
    WEND;                                                                  \
    SBAR;                                                                  \
  }

  // prologue: tile0 fully + tile1.Kh0 (12 loads); confirm tile0
  STAGE(gA, lA, 0, 0); STAGE(gB, lB, 0, 0);
  STAGE(gA, lA, 0, 1); STAGE(gB, lB, 0, 1);
  STAGE(gA, lA, 1, 0); STAGE(gB, lB, 1, 0);
  asm volatile("s_waitcnt vmcnt(4)" ::: "memory");
  SBAR;

  for (int T = 0; T < 16; ++T) {
    const int d = T & 1;
    PHASE(0, 0, { if (T < 15) STAGE(gA, lA, T + 1, 1); }, {});
    PHASE(1, 0, { if (T < 15) STAGE(gB, lB, T + 1, 1); },
          {
            if (T < 15) { asm volatile("s_waitcnt vmcnt(8)" ::: "memory"); }
            else        { asm volatile("s_waitcnt vmcnt(0)" ::: "memory"); }
          });
    PHASE(0, 1, { if (T < 14) STAGE(gA, lA, T + 2, 0); }, {});
    PHASE(1, 1, { if (T < 14) STAGE(gB, lB, T + 2, 0); },
          {
            if (T < 14)       { asm volatile("s_waitcnt vmcnt(8)" ::: "memory"); }
            else if (T == 14) { asm volatile("s_waitcnt vmcnt(4)" ::: "memory"); }
          });
  }
#undef STAGE
#undef PHASE

  // epilogue: bias + activation + store
#pragma unroll
  for (int ni = 0; ni < 4; ++ni) {
    int col  = n0 + wn * 64 + ni * 16 + (lane & 15);
    float bv = bias[col];
#pragma unroll
    for (int mi = 0; mi < 8; ++mi) {
      int r0 = m0 + wm * 128 + mi * 16 + ((lane >> 4) << 2);
      if constexpr (TRANS) {
        int b  = r0 >> 12;
        int l0 = r0 & 4095;
        half4 hv;
#pragma unroll
        for (int i = 0; i < 4; ++i) {
          float v = acc[mi][ni][i] + bv;
          if constexpr (ACT == 1) v = (v > 0.f) ? (v + 1.f) : __expf(v);
          hv[i] = (_Float16)v;
        }
        *(half4*)((_Float16*)Y + ((size_t)(b * 1024 + col)) * 4096 + l0) = hv;
      } else {
#pragma unroll
        for (int i = 0; i < 4; ++i) {
          float v = acc[mi][ni][i] + bv;
          if constexpr (ACT == 1) v = (v > 0.f) ? (v + 1.f) : __expf(v);
          Y[(size_t)(r0 + i) * NDIM + col] = (TOUT)v;
        }
      }
    }
  }
}

// ---------------------------------------------------------------------------
// kv_mfma: per (bh, chunk): partial C'[e][d] = sum_l VT[e][l]*KT[d][l]
// over l in [ch*512, ch*512+512). A = VT rows + synthesized ones-row
// (m-frag 4 -> Ksum); B = KT rows. fp16 partials.
// ---------------------------------------------------------------------------
__global__ __launch_bounds__(256, 2)
void kv_mfma(const _Float16* __restrict__ KT, const _Float16* __restrict__ VT,
             _Float16* __restrict__ pKV) {
  const int bh = blockIdx.x;      // 0..63
  const int ch = blockIdx.y;      // 0..7
  const int tid  = threadIdx.x;
  const int lane = tid & 63;
  const int w    = tid >> 6;

  __shared__ _Float16 As[64 * 64];  // VT tile
  __shared__ _Float16 Bs[64 * 64];  // KT tile

  const int lr = lane >> 3;
  const int ls = (lane & 7) ^ lr;
  const size_t lbase = (size_t)ch * 512 + ls * 8;
  const _Float16* gA = VT + (size_t)(bh * 64 + w * 16 + lr) * 4096 + lbase;
  const _Float16* gB = KT + (size_t)(bh * 64 + w * 16 + lr) * 4096 + lbase;
  _Float16* ldsA = As + (w * 16) * 64;
  _Float16* ldsB = Bs + (w * 16) * 64;

  half8 aones;
#pragma unroll
  for (int j = 0; j < 8; ++j) aones[j] = (lane & 15) == 0 ? (_Float16)1.0f : (_Float16)0.0f;

  f32x4 acc[5] = {};

  for (int k0 = 0; k0 < 512; k0 += 64) {
    __syncthreads();
#pragma unroll
    for (int c = 0; c < 2; ++c) {
      GLD_LDS16(gA + k0 + (size_t)(c * 8) * 4096, ldsA + c * 8 * 64);
      GLD_LDS16(gB + k0 + (size_t)(c * 8) * 4096, ldsB + c * 8 * 64);
    }
    __syncthreads();

    half8 afr[4][2], bfr[2];
#pragma unroll
    for (int m = 0; m < 4; ++m)
#pragma unroll
      for (int kk = 0; kk < 2; ++kk) {
        int row  = m * 16 + (lane & 15);
        int byte = row * 128 + ((lane >> 4) << 4) + kk * 64;
        byte ^= (row & 7) << 4;
        afr[m][kk] = *(const half8*)((const char*)As + byte);
      }
#pragma unroll
    for (int kk = 0; kk < 2; ++kk) {
      int row  = w * 16 + (lane & 15);
      int byte = row * 128 + ((lane >> 4) << 4) + kk * 64;
      byte ^= (row & 7) << 4;
      bfr[kk] = *(const half8*)((const char*)Bs + byte);
    }
#pragma unroll
    for (int kk = 0; kk < 2; ++kk) {
#pragma unroll
      for (int m = 0; m < 4; ++m)
        acc[m] = __builtin_amdgcn_mfma_f32_16x16x32_f16(afr[m][kk], bfr[kk],
                                                        acc[m], 0, 0, 0);
      acc[4] = __builtin_amdgcn_mfma_f32_16x16x32_f16(aones, bfr[kk],
                                                      acc[4], 0, 0, 0);
    }
  }

  _Float16* outp = pKV + ((size_t)ch * 64 + bh) * 5120;
  const int col = w * 16 + (lane & 15);
#pragma unroll
  for (int m = 0; m < 5; ++m) {
#pragma unroll
    for (int i = 0; i < 4; ++i) {
      int row = m * 16 + ((lane >> 4) << 2) + i;
      outp[row * 64 + col] = (_Float16)acc[m][i];
    }
  }
}

// ---------------------------------------------------------------------------
// Combine 8 fp16 partials -> KVTx fp16 [64 bh][80 rows][64 cols]
// ---------------------------------------------------------------------------
__global__ __launch_bounds__(256)
void kv_combine(const _Float16* __restrict__ pKV, _Float16* __restrict__ KVTx) {
  int g = blockIdx.x * 256 + threadIdx.x;   // 0..327679
  int bh = g / 5120;
  int j  = g - bh * 5120;
  float s = 0.f;
#pragma unroll
  for (int ch = 0; ch < 8; ++ch)
    s += (float)pKV[((size_t)ch * 64 + bh) * 5120 + j];
  KVTx[(size_t)bh * 5120 + j] = (_Float16)s;
}

// ---------------------------------------------------------------------------
// attn: per (mtile, bh): att[m][e] = Z(m) * sum_d Q[m][d]*KV[d][e]
// B tile has 80 rows: 64 KVT rows + Ksum row (64) + 15 zero rows; the 5th
// n-fragment's column 0 yields the Z denominator per row via the same MFMA.
// ---------------------------------------------------------------------------
__global__ __launch_bounds__(256, 2)
void attn_kernel(const _Float16* __restrict__ Qp, const _Float16* __restrict__ KVTx,
                 _Float16* __restrict__ att) {
  const int mt = blockIdx.x;      // 0..31
  const int bh = blockIdx.y;      // 0..63
  const int b  = bh >> 4, h = bh & 15;
  const int tid = threadIdx.x;
  const int lane = tid & 63;
  const int w = tid >> 6;
  const size_t m0 = (size_t)b * 4096 + (size_t)mt * 128;

  __shared__ _Float16 As[128 * 64];
  __shared__ _Float16 Bs[80 * 64];

#pragma unroll
  for (int j = 0; j < 4; ++j) {
    int c    = tid + 256 * j;
    int row  = c >> 3;
    int col8 = (c & 7) << 3;
    int byte = row * 128 + (col8 << 1);
    byte ^= (row & 7) << 4;
    *(half8*)((char*)As + byte) =
        *(const half8*)(Qp + (m0 + row) * KDIM + h * 64 + col8);
  }
  for (int c = tid; c < 640; c += 256) {
    int row  = c >> 3;
    int col8 = (c & 7) << 3;
    int byte = row * 128 + (col8 << 1);
    byte ^= (row & 7) << 4;
    *(half8*)((char*)Bs + byte) = *(const half8*)(KVTx + (size_t)bh * 5120 + c * 8);
  }
  __syncthreads();

  f32x4 acc[2][5] = {};
  half8 afr[2][2], bfr[5][2];
#pragma unroll
  for (int m = 0; m < 2; ++m)
#pragma unroll
    for (int kk = 0; kk < 2; ++kk) {
      int row  = w * 32 + m * 16 + (lane & 15);
      int byte = row * 128 + ((lane >> 4) << 4) + kk * 64;
      byte ^= (row & 7) << 4;
      afr[m][kk] = *(const half8*)((const char*)As + byte);
    }
#pragma unroll
  for (int n = 0; n < 5; ++n)
#pragma unroll
    for (int kk = 0; kk < 2; ++kk) {
      int row  = n * 16 + (lane & 15);
      int byte = row * 128 + ((lane >> 4) << 4) + kk * 64;
      byte ^= (row & 7) << 4;
      bfr[n][kk] = *(const half8*)((const char*)Bs + byte);
    }
#pragma unroll
  for (int kk = 0; kk < 2; ++kk)
#pragma unroll
    for (int m = 0; m < 2; ++m)
#pragma unroll
      for (int n = 0; n < 5; ++n)
        acc[m][n] = __builtin_amdgcn_mfma_f32_16x16x32_f16(afr[m][kk], bfr[n][kk],
                                                           acc[m][n], 0, 0, 0);

#pragma unroll
  for (int m = 0; m < 2; ++m) {
#pragma unroll
    for (int i = 0; i < 4; ++i) {
      float dn = __shfl(acc[m][4][i], lane & 48);
      float z  = 1.f / (dn + 1e-6f);
      size_t row = m0 + w * 32 + m * 16 + ((lane >> 4) << 2) + i;
#pragma unroll
      for (int n = 0; n < 4; ++n) {
        att[row * NDIM + h * 64 + n * 16 + (lane & 15)] =
            (_Float16)(acc[m][n][i] * z);
      }
    }
  }
}

// ---------------------------------------------------------------------------
extern "C" void kernel_launch(void* const* d_in, const int* in_sizes, int n_in,
                              void* d_out, int out_size, void* d_ws, size_t ws_size,
                              hipStream_t stream) {
  const float* q  = (const float*)d_in[0];
  const float* k  = (const float*)d_in[1];
  const float* v  = (const float*)d_in[2];
  const float* wq = (const float*)d_in[3];
  const float* bq = (const float*)d_in[4];
  const float* wk = (const float*)d_in[5];
  const float* bk = (const float*)d_in[6];
  const float* wv = (const float*)d_in[7];
  const float* bv = (const float*)d_in[8];
  const float* wo = (const float*)d_in[9];
  const float* bo = (const float*)d_in[10];
  float* out = (float*)d_out;

  char* ws = (char*)d_ws;
  _Float16* Qp   = (_Float16*)(ws);                    // 33,554,432 B
  _Float16* KT   = (_Float16*)(ws + 33554432);         // 33,554,432 B (att aliases)
  _Float16* VT   = (_Float16*)(ws + 67108864);         // 33,554,432 B
  _Float16* Wh   = (_Float16*)(ws + 100663296);        //  2,097,152 B (reused 4x)
  _Float16* pKVh = (_Float16*)(ws + 102760448);        //  5,242,880 B
  _Float16* KVTx = (_Float16*)(ws + 108003328);        //    655,360 B
  _Float16* att  = KT;                                 // reuse KT after KV built
  _Float16* Xh   = (_Float16*)d_out;                   // fp16 X scratch in d_out

  const int N8_BIG = MROWS * KDIM / 8;   // 2,097,152
  const int N8_W   = KDIM * KDIM / 8;    //   131,072

  const int GBLK = (MROWS / 256) * (NDIM / 256);   // 256 blocks

  // Q projection (natural layout)
  cvt_f32_to_f16<<<2048, 256, 0, stream>>>(q, Xh, N8_BIG);
  cvt_f32_to_f16<<<512, 256, 0, stream>>>(wq, Wh, N8_W);
  gemm_8p<1, 0, _Float16><<<GBLK, 512, 0, stream>>>(Xh, Wh, bq, Qp);
  // K projection (transposed per-head: KT[bh][d][l])
  cvt_f32_to_f16<<<2048, 256, 0, stream>>>(k, Xh, N8_BIG);
  cvt_f32_to_f16<<<512, 256, 0, stream>>>(wk, Wh, N8_W);
  gemm_8p<1, 1, _Float16><<<GBLK, 512, 0, stream>>>(Xh, Wh, bk, KT);
  // V projection (transposed per-head: VT[bh][e][l])
  cvt_f32_to_f16<<<2048, 256, 0, stream>>>(v, Xh, N8_BIG);
  cvt_f32_to_f16<<<512, 256, 0, stream>>>(wv, Wh, N8_W);
  gemm_8p<0, 1, _Float16><<<GBLK, 512, 0, stream>>>(Xh, Wh, bv, VT);

  kv_mfma<<<dim3(64, 8), 256, 0, stream>>>(KT, VT, pKVh);
  kv_combine<<<1280, 256, 0, stream>>>(pKVh, KVTx);

  attn_kernel<<<dim3(32, 64), 256, 0, stream>>>(Qp, KVTx, att);

  // output projection (writes d_out; Xh scratch is dead by now)
  cvt_f32_to_f16<<<512, 256, 0, stream>>>(wo, Wh, N8_W);
  gemm_8p<0, 0, float><<<GBLK, 512, 0, stream>>>(att, Wh, bo, out);
}